// Round 4
// baseline (2021.066 us; speedup 1.0000x reference)
//
#include <hip/hip_runtime.h>
#include <cstdint>
#include <cstddef>

static constexpr int N_NODES = 100000;
static constexpr int N_GRAPHS = 256;
static constexpr int HF = 64;

#define SCAN_T 256
#define SCAN_E 8
#define SCAN_CHUNK (SCAN_T * SCAN_E)

#define BSHIFT 9
#define BNODES 512
#define ECHUNK 16384

// ---------- exclusive scan (3-pass) ----------
__global__ void scan1_k(const int* __restrict__ in, int* __restrict__ out,
                        int* __restrict__ sums, int n) {
    __shared__ int lds[SCAN_T];
    int t = threadIdx.x;
    int base = blockIdx.x * SCAN_CHUNK + t * SCAN_E;
    int v[SCAN_E];
    int s = 0;
#pragma unroll
    for (int i = 0; i < SCAN_E; ++i) {
        int idx = base + i;
        int x = (idx < n) ? in[idx] : 0;
        v[i] = s; s += x;
    }
    lds[t] = s; __syncthreads();
    for (int off = 1; off < SCAN_T; off <<= 1) {
        int a = (t >= off) ? lds[t - off] : 0;
        __syncthreads();
        lds[t] += a;
        __syncthreads();
    }
    int excl = (t == 0) ? 0 : lds[t - 1];
    if (t == SCAN_T - 1) sums[blockIdx.x] = lds[SCAN_T - 1];
#pragma unroll
    for (int i = 0; i < SCAN_E; ++i) {
        int idx = base + i;
        if (idx < n) out[idx] = excl + v[i];
    }
}

__global__ void scan2_k(int* __restrict__ sums, int nb) {
    __shared__ int lds[SCAN_T];
    int t = threadIdx.x;
    lds[t] = (t < nb) ? sums[t] : 0;
    __syncthreads();
    for (int off = 1; off < SCAN_T; off <<= 1) {
        int a = (t >= off) ? lds[t - off] : 0;
        __syncthreads();
        lds[t] += a;
        __syncthreads();
    }
    int excl = (t == 0) ? 0 : lds[t - 1];
    if (t < nb) sums[t] = excl;
}

__global__ void scan3_k(int* __restrict__ out, const int* __restrict__ sums, int n) {
    int idx = blockIdx.x * blockDim.x + threadIdx.x;
    if (idx < n) out[idx] += sums[idx / SCAN_CHUNK];
}

// ---------- per-chunk bucket histogram ----------
__global__ void bhist_k(const int* __restrict__ dst, int* __restrict__ cnt,
                        int E, int nblk, int NB) {
    __shared__ int c[256];
    int t = threadIdx.x;
    c[t] = 0;
    __syncthreads();
    int base = blockIdx.x * ECHUNK;
    for (int i = t; i < ECHUNK; i += 256) {
        int e = base + i;
        if (e >= E) break;
        atomicAdd(&c[dst[e] >> BSHIFT], 1);
    }
    __syncthreads();
    if (t < NB) cnt[t * nblk + blockIdx.x] = c[t];
}

// ---------- scatter edges into bucket partitions ----------
__global__ void scatter_k(const int* __restrict__ src, const int* __restrict__ dst,
                          const int* __restrict__ scn, int2* __restrict__ es,
                          int E, int nblk, int NB) {
    __shared__ int offs[256];
    int t = threadIdx.x;
    if (t < NB) offs[t] = scn[t * nblk + blockIdx.x];
    __syncthreads();
    int base = blockIdx.x * ECHUNK;
    for (int i = t; i < ECHUNK; i += 256) {
        int e = base + i;
        if (e >= E) break;
        int d = dst[e];
        int b = d >> BSHIFT;
        int p = atomicAdd(&offs[b], 1);
        es[p] = make_int2(src[e], d);
    }
}

// ---------- per-bucket: local deg, row_ptr, dinv, CSR col fill ----------
__global__ void fill2_k(const int2* __restrict__ es, const int* __restrict__ scn,
                        int* __restrict__ rowp, int* __restrict__ deg,
                        float* __restrict__ dinv, int* __restrict__ col,
                        int E, int nblk, int NB, int N) {
    __shared__ int ldeg[BNODES];
    __shared__ int rp[BNODES];
    __shared__ int ps[256];
    int b = blockIdx.x, t = threadIdx.x;
    int ebase = scn[b * nblk];
    int eend = (b + 1 < NB) ? scn[(b + 1) * nblk] : E;
    int d0 = b << BSHIFT;
    int nd = min(BNODES, N - d0);
    ldeg[t] = 0; ldeg[t + 256] = 0;
    __syncthreads();
    for (int e = ebase + t; e < eend; e += 256) atomicAdd(&ldeg[es[e].y - d0], 1);
    __syncthreads();
    // exclusive scan of ldeg[0..511] -> rp
    int a0 = ldeg[2 * t], a1 = ldeg[2 * t + 1];
    ps[t] = a0 + a1;
    __syncthreads();
    for (int off = 1; off < 256; off <<= 1) {
        int v = (t >= off) ? ps[t - off] : 0;
        __syncthreads();
        ps[t] += v;
        __syncthreads();
    }
    int ex = (t == 0) ? 0 : ps[t - 1];
    rp[2 * t] = ex;
    rp[2 * t + 1] = ex + a0;
    __syncthreads();
    for (int i = t; i < nd; i += 256) {
        int d = d0 + i;
        rowp[d] = ebase + rp[i];
        int dg = ldeg[i];
        deg[d] = dg;
        dinv[d] = rsqrtf((float)(dg + 1));
    }
    __syncthreads();
    ldeg[t] = 0; ldeg[t + 256] = 0;  // reuse as position counters
    __syncthreads();
    for (int e = ebase + t; e < eend; e += 256) {
        int2 ed = es[e];
        int li = ed.y - d0;
        int p = atomicAdd(&ldeg[li], 1);
        col[ebase + rp[li] + p] = ed.x;
    }
}

// ---------- W transpose: W4[k4*64+c] = {W[4k4..4k4+3][c]} ----------
__global__ void wtrans_k(const float* __restrict__ W, float4* __restrict__ W4, int total) {
    int idx = blockIdx.x * blockDim.x + threadIdx.x;
    if (idx >= total) return;
    int k4 = idx >> 6, c = idx & 63;
    W4[idx] = make_float4(W[(4 * k4 + 0) * HF + c], W[(4 * k4 + 1) * HF + c],
                          W[(4 * k4 + 2) * HF + c], W[(4 * k4 + 3) * HF + c]);
}

// ---------- u = (in @ W) * dinv[row]  (LDS-tiled: 64 rows x 64-k chunks) ----------
// Block = 256 threads (4 waves); wave handles 16 rows; lane = out column.
template <int K>
__global__ __launch_bounds__(256) void gemm3_k(const float* __restrict__ in,
                                               const float4* __restrict__ W4,
                                               const float* __restrict__ dinv,
                                               float* __restrict__ u, int n) {
    __shared__ float4 Wl[16 * HF];   // W chunk: [16 k4][64 col], 16 KB
    __shared__ float4 Xl[64 * 17];   // x chunk: [64 row][16 k4 + pad], 17.4 KB
    int t = threadIdx.x;
    int wave = t >> 6, lane = t & 63;
    int rb = blockIdx.x * 64;
    float acc[16];
#pragma unroll
    for (int i = 0; i < 16; ++i) acc[i] = 0.f;
    constexpr int NC = K / 64;
#pragma unroll
    for (int kc = 0; kc < NC; ++kc) {
        // stage W chunk (coalesced, L2-hot)
        {
            const float4* Wc = W4 + kc * 16 * HF;
            for (int i = t; i < 16 * HF; i += 256) Wl[i] = Wc[i];
        }
        // stage x chunk: row = t>>4 (+16 per iter), q = t&15 -> 256B runs per row
        {
            int r = t >> 4, q = t & 15;
#pragma unroll
            for (int i = 0; i < 4; ++i) {
                int row = r + i * 16;
                int gr = rb + row;
                float4 v = (gr < n)
                    ? *(const float4*)(in + (size_t)gr * K + kc * 64 + q * 4)
                    : make_float4(0.f, 0.f, 0.f, 0.f);
                Xl[row * 17 + q] = v;
            }
        }
        __syncthreads();
        int r0 = wave * 16;
#pragma unroll
        for (int k4 = 0; k4 < 16; ++k4) {
            float4 w = Wl[k4 * HF + lane];     // contiguous 1KB wave read
#pragma unroll
            for (int r = 0; r < 16; ++r) {
                float4 v = Xl[(r0 + r) * 17 + k4];  // broadcast read
                acc[r] = fmaf(v.x, w.x, fmaf(v.y, w.y, fmaf(v.z, w.z, fmaf(v.w, w.w, acc[r]))));
            }
        }
        __syncthreads();
    }
#pragma unroll
    for (int r = 0; r < 16; ++r) {
        int row = rb + wave * 16 + r;
        if (row < n) u[(size_t)row * HF + lane] = acc[r] * dinv[row];
    }
}

// ---------- aggregation: out[v] = relu(dinv[v]*(sum_in u[s] + u[v]) + b) ----------
__global__ void agg_k(const float* __restrict__ u, const int* __restrict__ col,
                      const int* __restrict__ row_ptr, const int* __restrict__ deg,
                      const float* __restrict__ dinv, const float* __restrict__ bias,
                      float* __restrict__ out, int n) {
    int wave = threadIdx.x >> 6, lane = threadIdx.x & 63;
    int v = blockIdx.x * 4 + wave;
    if (v >= n) return;
    int start = row_ptr[v];
    int end = start + deg[v];
    float acc = u[(size_t)v * HF + lane];  // self loop
    for (int e = start; e < end;) {
        int m = min(64, end - e);
        int c = (lane < m) ? col[e + lane] : 0;
        int t = 0;
        for (; t + 4 <= m; t += 4) {
            int s0 = __shfl(c, t), s1 = __shfl(c, t + 1);
            int s2 = __shfl(c, t + 2), s3 = __shfl(c, t + 3);
            float a0 = u[(size_t)s0 * HF + lane];
            float a1 = u[(size_t)s1 * HF + lane];
            float a2 = u[(size_t)s2 * HF + lane];
            float a3 = u[(size_t)s3 * HF + lane];
            acc += a0; acc += a1; acc += a2; acc += a3;
        }
        for (; t < m; ++t) {
            int s = __shfl(c, t);
            acc += u[(size_t)s * HF + lane];
        }
        e += m;
    }
    out[(size_t)v * HF + lane] = fmaxf(fmaf(acc, dinv[v], bias[lane]), 0.f);
}

// ---------- fused mean-pool + linear head ----------
__device__ __forceinline__ int lower_bound_i(const int* a, int n, int key) {
    int lo = 0, hi = n;
    while (lo < hi) { int mid = (lo + hi) >> 1; if (a[mid] < key) lo = mid + 1; else hi = mid; }
    return lo;
}

__global__ void pool_head_k(const float* __restrict__ h, const int* __restrict__ batch,
                            const float* __restrict__ Wl, const float* __restrict__ bl,
                            float* __restrict__ out, int n) {
    __shared__ float ssum[4][HF];
    __shared__ float smean[HF];
    int g = blockIdx.x;
    int wave = threadIdx.x >> 6, lane = threadIdx.x & 63;
    int start = lower_bound_i(batch, n, g);
    int end = lower_bound_i(batch, n, g + 1);
    float acc = 0.f;
    for (int v = start + wave; v < end; v += 4) acc += h[(size_t)v * HF + lane];
    ssum[wave][lane] = acc;
    __syncthreads();
    if (wave == 0) {
        float s = ssum[0][lane] + ssum[1][lane] + ssum[2][lane] + ssum[3][lane];
        float cnt = (float)(end - start);
        smean[lane] = s / fmaxf(cnt, 1.f);
    }
    __syncthreads();
    if (threadIdx.x < 2) {
        float o = bl[threadIdx.x];
        for (int j = 0; j < HF; ++j) o += smean[j] * Wl[j * 2 + threadIdx.x];
        out[g * 2 + threadIdx.x] = o;
    }
}

extern "C" void kernel_launch(void* const* d_in, const int* in_sizes, int n_in,
                              void* d_out, int out_size, void* d_ws, size_t ws_size,
                              hipStream_t stream) {
    const float* x     = (const float*)d_in[0];
    const int*   ei    = (const int*)d_in[1];
    const int*   batch = (const int*)d_in[2];
    const float* W1 = (const float*)d_in[3];
    const float* b1 = (const float*)d_in[4];
    const float* W2 = (const float*)d_in[5];
    const float* b2 = (const float*)d_in[6];
    const float* W3 = (const float*)d_in[7];
    const float* b3 = (const float*)d_in[8];
    const float* Wl = (const float*)d_in[9];
    const float* bl = (const float*)d_in[10];
    float* outp = (float*)d_out;

    const int N = N_NODES;
    const int E = in_sizes[1] / 2;
    const int NB = (N + BNODES - 1) >> BSHIFT;        // 196 buckets
    const int NBLK = (E + ECHUNK - 1) / ECHUNK;       // edge chunks
    const int M = NB * NBLK;                          // (bucket, chunk) counts

    char* ws = (char*)d_ws;
    size_t off = 0;
    auto alloc = [&](size_t bytes) {
        void* p = ws + off;
        off = (off + bytes + 255) & ~size_t(255);
        return p;
    };
    float*  P    = (float*)alloc((size_t)N * HF * 4);
    float*  U    = (float*)alloc((size_t)N * HF * 4);   // also holds sorted edges (int2)
    int*    colA = (int*)alloc((size_t)E * 4);
    int*    deg  = (int*)alloc((size_t)N * 4);
    float*  dinv = (float*)alloc((size_t)N * 4);
    int*    rowp = (int*)alloc((size_t)N * 4);
    int*    cnt  = (int*)alloc((size_t)M * 4);
    int*    scn  = (int*)alloc((size_t)M * 4);
    int*    sums = (int*)alloc(1024);
    float4* W4_1 = (float4*)alloc((size_t)(128 / 4) * HF * 16);
    float4* W4_2 = (float4*)alloc((size_t)(64 / 4) * HF * 16);
    float4* W4_3 = (float4*)alloc((size_t)(64 / 4) * HF * 16);
    int2*   es   = (int2*)U;
    (void)ws_size; (void)n_in; (void)out_size;

    const int* src = ei;
    const int* dst = ei + E;

    // ---- build bucket-sorted edge list + CSR ----
    bhist_k<<<NBLK, 256, 0, stream>>>(dst, cnt, E, NBLK, NB);
    int nb = (M + SCAN_CHUNK - 1) / SCAN_CHUNK;
    scan1_k<<<nb, SCAN_T, 0, stream>>>(cnt, scn, sums, M);
    scan2_k<<<1, SCAN_T, 0, stream>>>(sums, nb);
    scan3_k<<<(M + 255) / 256, 256, 0, stream>>>(scn, sums, M);
    scatter_k<<<NBLK, 256, 0, stream>>>(src, dst, scn, es, E, NBLK, NB);
    fill2_k<<<NB, 256, 0, stream>>>(es, scn, rowp, deg, dinv, colA, E, NBLK, NB, N);

    // one-time W transforms (cheap)
    wtrans_k<<<(32 * HF + 255) / 256, 256, 0, stream>>>(W1, W4_1, 32 * HF);
    wtrans_k<<<(16 * HF + 255) / 256, 256, 0, stream>>>(W2, W4_2, 16 * HF);
    wtrans_k<<<(16 * HF + 255) / 256, 256, 0, stream>>>(W3, W4_3, 16 * HF);

    int gRow = (N + 3) / 4;       // agg: 4 nodes/block
    int gRow64 = (N + 63) / 64;   // gemm: 64 rows/block
    // layer 1 (K=128)
    gemm3_k<128><<<gRow64, 256, 0, stream>>>(x, W4_1, dinv, U, N);
    agg_k<<<gRow, 256, 0, stream>>>(U, colA, rowp, deg, dinv, b1, P, N);
    // layer 2 (K=64)
    gemm3_k<64><<<gRow64, 256, 0, stream>>>(P, W4_2, dinv, U, N);
    agg_k<<<gRow, 256, 0, stream>>>(U, colA, rowp, deg, dinv, b2, P, N);
    // layer 3 (K=64)
    gemm3_k<64><<<gRow64, 256, 0, stream>>>(P, W4_3, dinv, U, N);
    agg_k<<<gRow, 256, 0, stream>>>(U, colA, rowp, deg, dinv, b3, P, N);

    pool_head_k<<<N_GRAPHS, 256, 0, stream>>>(P, batch, Wl, bl, outp, N);
}

// Round 5
// 582.905 us; speedup vs baseline: 3.4672x; 3.4672x over previous
//
#include <hip/hip_runtime.h>
#include <cstdint>
#include <cstddef>

static constexpr int N_NODES = 100000;
static constexpr int N_GRAPHS = 256;
static constexpr int HF = 64;

#define SCAN_T 256
#define SCAN_E 8
#define SCAN_CHUNK (SCAN_T * SCAN_E)

#define BSHIFT 9
#define BNODES 512
#define ECHUNK 16384

// ---------- exclusive scan (3-pass) ----------
__global__ void scan1_k(const int* __restrict__ in, int* __restrict__ out,
                        int* __restrict__ sums, int n) {
    __shared__ int lds[SCAN_T];
    int t = threadIdx.x;
    int base = blockIdx.x * SCAN_CHUNK + t * SCAN_E;
    int v[SCAN_E];
    int s = 0;
#pragma unroll
    for (int i = 0; i < SCAN_E; ++i) {
        int idx = base + i;
        int x = (idx < n) ? in[idx] : 0;
        v[i] = s; s += x;
    }
    lds[t] = s; __syncthreads();
    for (int off = 1; off < SCAN_T; off <<= 1) {
        int a = (t >= off) ? lds[t - off] : 0;
        __syncthreads();
        lds[t] += a;
        __syncthreads();
    }
    int excl = (t == 0) ? 0 : lds[t - 1];
    if (t == SCAN_T - 1) sums[blockIdx.x] = lds[SCAN_T - 1];
#pragma unroll
    for (int i = 0; i < SCAN_E; ++i) {
        int idx = base + i;
        if (idx < n) out[idx] = excl + v[i];
    }
}

__global__ void scan2_k(int* __restrict__ sums, int nb) {
    __shared__ int lds[SCAN_T];
    int t = threadIdx.x;
    lds[t] = (t < nb) ? sums[t] : 0;
    __syncthreads();
    for (int off = 1; off < SCAN_T; off <<= 1) {
        int a = (t >= off) ? lds[t - off] : 0;
        __syncthreads();
        lds[t] += a;
        __syncthreads();
    }
    int excl = (t == 0) ? 0 : lds[t - 1];
    if (t < nb) sums[t] = excl;
}

__global__ void scan3_k(int* __restrict__ out, const int* __restrict__ sums, int n) {
    int idx = blockIdx.x * blockDim.x + threadIdx.x;
    if (idx < n) out[idx] += sums[idx / SCAN_CHUNK];
}

// ---------- per-chunk bucket histogram ----------
__global__ void bhist_k(const int* __restrict__ dst, int* __restrict__ cnt,
                        int E, int nblk, int NB) {
    __shared__ int c[256];
    int t = threadIdx.x;
    c[t] = 0;
    __syncthreads();
    int base = blockIdx.x * ECHUNK;
    for (int i = t; i < ECHUNK; i += 256) {
        int e = base + i;
        if (e >= E) break;
        atomicAdd(&c[dst[e] >> BSHIFT], 1);
    }
    __syncthreads();
    if (t < NB) cnt[t * nblk + blockIdx.x] = c[t];
}

// ---------- scatter edges into bucket partitions ----------
__global__ void scatter_k(const int* __restrict__ src, const int* __restrict__ dst,
                          const int* __restrict__ scn, int2* __restrict__ es,
                          int E, int nblk, int NB) {
    __shared__ int offs[256];
    int t = threadIdx.x;
    if (t < NB) offs[t] = scn[t * nblk + blockIdx.x];
    __syncthreads();
    int base = blockIdx.x * ECHUNK;
    for (int i = t; i < ECHUNK; i += 256) {
        int e = base + i;
        if (e >= E) break;
        int d = dst[e];
        int b = d >> BSHIFT;
        int p = atomicAdd(&offs[b], 1);
        es[p] = make_int2(src[e], d);
    }
}

// ---------- per-bucket: local deg, row_ptr, dinv, CSR col fill ----------
__global__ void fill2_k(const int2* __restrict__ es, const int* __restrict__ scn,
                        int* __restrict__ rowp, int* __restrict__ deg,
                        float* __restrict__ dinv, int* __restrict__ col,
                        int E, int nblk, int NB, int N) {
    __shared__ int ldeg[BNODES];
    __shared__ int rp[BNODES];
    __shared__ int ps[256];
    int b = blockIdx.x, t = threadIdx.x;
    int ebase = scn[b * nblk];
    int eend = (b + 1 < NB) ? scn[(b + 1) * nblk] : E;
    int d0 = b << BSHIFT;
    int nd = min(BNODES, N - d0);
    ldeg[t] = 0; ldeg[t + 256] = 0;
    __syncthreads();
    for (int e = ebase + t; e < eend; e += 256) atomicAdd(&ldeg[es[e].y - d0], 1);
    __syncthreads();
    // exclusive scan of ldeg[0..511] -> rp
    int a0 = ldeg[2 * t], a1 = ldeg[2 * t + 1];
    ps[t] = a0 + a1;
    __syncthreads();
    for (int off = 1; off < 256; off <<= 1) {
        int v = (t >= off) ? ps[t - off] : 0;
        __syncthreads();
        ps[t] += v;
        __syncthreads();
    }
    int ex = (t == 0) ? 0 : ps[t - 1];
    rp[2 * t] = ex;
    rp[2 * t + 1] = ex + a0;
    __syncthreads();
    for (int i = t; i < nd; i += 256) {
        int d = d0 + i;
        rowp[d] = ebase + rp[i];
        int dg = ldeg[i];
        deg[d] = dg;
        dinv[d] = rsqrtf((float)(dg + 1));
    }
    __syncthreads();
    ldeg[t] = 0; ldeg[t + 256] = 0;  // reuse as position counters
    __syncthreads();
    for (int e = ebase + t; e < eend; e += 256) {
        int2 ed = es[e];
        int li = ed.y - d0;
        int p = atomicAdd(&ldeg[li], 1);
        col[ebase + rp[li] + p] = ed.x;
    }
}

// ---------- W transpose: W4[k4*64+c] = {W[4k4..4k4+3][c]} ----------
__global__ void wtrans_k(const float* __restrict__ W, float4* __restrict__ W4, int total) {
    int idx = blockIdx.x * blockDim.x + threadIdx.x;
    if (idx >= total) return;
    int k4 = idx >> 6, c = idx & 63;
    W4[idx] = make_float4(W[(4 * k4 + 0) * HF + c], W[(4 * k4 + 1) * HF + c],
                          W[(4 * k4 + 2) * HF + c], W[(4 * k4 + 3) * HF + c]);
}

// ---------- u = (in @ W) * dinv[row]  (LDS-tiled, register-pressure-capped) ----------
// Block = 256 threads (4 waves), 64 rows/block, 16 rows/wave, lane = out col.
// launch_bounds(256,4): VGPR<=128, 4 blocks/CU with 33KB LDS.
// kc/k4 loops kept rolled (unroll 1) to stop ds_read pipelining from spilling.
template <int K>
__global__ __launch_bounds__(256, 4) void gemm4_k(const float* __restrict__ in,
                                                  const float4* __restrict__ W4,
                                                  const float* __restrict__ dinv,
                                                  float* __restrict__ u, int n) {
    __shared__ float4 Wl[16 * HF];   // W chunk: [16 k4][64 col], 16 KB
    __shared__ float4 Xl[64 * 17];   // x chunk: [64 row][16 k4 + pad], 17.4 KB
    int t = threadIdx.x;
    int wave = t >> 6, lane = t & 63;
    int rb = blockIdx.x * 64;
    float acc[16];
#pragma unroll
    for (int i = 0; i < 16; ++i) acc[i] = 0.f;
    constexpr int NC = K / 64;
#pragma unroll 1
    for (int kc = 0; kc < NC; ++kc) {
        // stage W chunk (coalesced, L2-hot)
        const float4* Wc = W4 + kc * 16 * HF;
#pragma unroll 1
        for (int i = t; i < 16 * HF; i += 256) Wl[i] = Wc[i];
        // stage x chunk: thread (r=t>>4, q=t&15) -> 256B coalesced runs per row
        {
            int r = t >> 4, q = t & 15;
#pragma unroll 1
            for (int i = 0; i < 4; ++i) {
                int row = r + i * 16;
                int gr = rb + row;
                float4 v = (gr < n)
                    ? *(const float4*)(in + (size_t)gr * K + kc * 64 + q * 4)
                    : make_float4(0.f, 0.f, 0.f, 0.f);
                Xl[row * 17 + q] = v;
            }
        }
        __syncthreads();
        int r0 = wave * 16;
#pragma unroll 1
        for (int k4 = 0; k4 < 16; ++k4) {
            float4 w = Wl[k4 * HF + lane];     // contiguous 1KB wave read
#pragma unroll
            for (int r = 0; r < 16; ++r) {
                float4 v = Xl[(r0 + r) * 17 + k4];  // same-addr broadcast read
                acc[r] = fmaf(v.x, w.x, fmaf(v.y, w.y, fmaf(v.z, w.z, fmaf(v.w, w.w, acc[r]))));
            }
        }
        __syncthreads();
    }
#pragma unroll 1
    for (int r = 0; r < 16; ++r) {
        int row = rb + wave * 16 + r;
        if (row < n) u[(size_t)row * HF + lane] = acc[r] * dinv[row];
    }
}

// ---------- aggregation: out[v] = relu(dinv[v]*(sum_in u[s] + u[v]) + b) ----------
__global__ void agg_k(const float* __restrict__ u, const int* __restrict__ col,
                      const int* __restrict__ row_ptr, const int* __restrict__ deg,
                      const float* __restrict__ dinv, const float* __restrict__ bias,
                      float* __restrict__ out, int n) {
    int wave = threadIdx.x >> 6, lane = threadIdx.x & 63;
    int v = blockIdx.x * 4 + wave;
    if (v >= n) return;
    int start = row_ptr[v];
    int end = start + deg[v];
    float acc = u[(size_t)v * HF + lane];  // self loop
    for (int e = start; e < end;) {
        int m = min(64, end - e);
        int c = (lane < m) ? col[e + lane] : 0;
        int t = 0;
        for (; t + 4 <= m; t += 4) {
            int s0 = __shfl(c, t), s1 = __shfl(c, t + 1);
            int s2 = __shfl(c, t + 2), s3 = __shfl(c, t + 3);
            float a0 = u[(size_t)s0 * HF + lane];
            float a1 = u[(size_t)s1 * HF + lane];
            float a2 = u[(size_t)s2 * HF + lane];
            float a3 = u[(size_t)s3 * HF + lane];
            acc += a0; acc += a1; acc += a2; acc += a3;
        }
        for (; t < m; ++t) {
            int s = __shfl(c, t);
            acc += u[(size_t)s * HF + lane];
        }
        e += m;
    }
    out[(size_t)v * HF + lane] = fmaxf(fmaf(acc, dinv[v], bias[lane]), 0.f);
}

// ---------- fused mean-pool + linear head ----------
__device__ __forceinline__ int lower_bound_i(const int* a, int n, int key) {
    int lo = 0, hi = n;
    while (lo < hi) { int mid = (lo + hi) >> 1; if (a[mid] < key) lo = mid + 1; else hi = mid; }
    return lo;
}

__global__ void pool_head_k(const float* __restrict__ h, const int* __restrict__ batch,
                            const float* __restrict__ Wl, const float* __restrict__ bl,
                            float* __restrict__ out, int n) {
    __shared__ float ssum[4][HF];
    __shared__ float smean[HF];
    int g = blockIdx.x;
    int wave = threadIdx.x >> 6, lane = threadIdx.x & 63;
    int start = lower_bound_i(batch, n, g);
    int end = lower_bound_i(batch, n, g + 1);
    float acc = 0.f;
    for (int v = start + wave; v < end; v += 4) acc += h[(size_t)v * HF + lane];
    ssum[wave][lane] = acc;
    __syncthreads();
    if (wave == 0) {
        float s = ssum[0][lane] + ssum[1][lane] + ssum[2][lane] + ssum[3][lane];
        float cnt = (float)(end - start);
        smean[lane] = s / fmaxf(cnt, 1.f);
    }
    __syncthreads();
    if (threadIdx.x < 2) {
        float o = bl[threadIdx.x];
        for (int j = 0; j < HF; ++j) o += smean[j] * Wl[j * 2 + threadIdx.x];
        out[g * 2 + threadIdx.x] = o;
    }
}

extern "C" void kernel_launch(void* const* d_in, const int* in_sizes, int n_in,
                              void* d_out, int out_size, void* d_ws, size_t ws_size,
                              hipStream_t stream) {
    const float* x     = (const float*)d_in[0];
    const int*   ei    = (const int*)d_in[1];
    const int*   batch = (const int*)d_in[2];
    const float* W1 = (const float*)d_in[3];
    const float* b1 = (const float*)d_in[4];
    const float* W2 = (const float*)d_in[5];
    const float* b2 = (const float*)d_in[6];
    const float* W3 = (const float*)d_in[7];
    const float* b3 = (const float*)d_in[8];
    const float* Wl = (const float*)d_in[9];
    const float* bl = (const float*)d_in[10];
    float* outp = (float*)d_out;

    const int N = N_NODES;
    const int E = in_sizes[1] / 2;
    const int NB = (N + BNODES - 1) >> BSHIFT;        // 196 buckets
    const int NBLK = (E + ECHUNK - 1) / ECHUNK;       // edge chunks
    const int M = NB * NBLK;                          // (bucket, chunk) counts

    char* ws = (char*)d_ws;
    size_t off = 0;
    auto alloc = [&](size_t bytes) {
        void* p = ws + off;
        off = (off + bytes + 255) & ~size_t(255);
        return p;
    };
    float*  P    = (float*)alloc((size_t)N * HF * 4);
    float*  U    = (float*)alloc((size_t)N * HF * 4);   // also holds sorted edges (int2)
    int*    colA = (int*)alloc((size_t)E * 4);
    int*    deg  = (int*)alloc((size_t)N * 4);
    float*  dinv = (float*)alloc((size_t)N * 4);
    int*    rowp = (int*)alloc((size_t)N * 4);
    int*    cnt  = (int*)alloc((size_t)M * 4);
    int*    scn  = (int*)alloc((size_t)M * 4);
    int*    sums = (int*)alloc(1024);
    float4* W4_1 = (float4*)alloc((size_t)(128 / 4) * HF * 16);
    float4* W4_2 = (float4*)alloc((size_t)(64 / 4) * HF * 16);
    float4* W4_3 = (float4*)alloc((size_t)(64 / 4) * HF * 16);
    int2*   es   = (int2*)U;
    (void)ws_size; (void)n_in; (void)out_size;

    const int* src = ei;
    const int* dst = ei + E;

    // ---- build bucket-sorted edge list + CSR ----
    bhist_k<<<NBLK, 256, 0, stream>>>(dst, cnt, E, NBLK, NB);
    int nb = (M + SCAN_CHUNK - 1) / SCAN_CHUNK;
    scan1_k<<<nb, SCAN_T, 0, stream>>>(cnt, scn, sums, M);
    scan2_k<<<1, SCAN_T, 0, stream>>>(sums, nb);
    scan3_k<<<(M + 255) / 256, 256, 0, stream>>>(scn, sums, M);
    scatter_k<<<NBLK, 256, 0, stream>>>(src, dst, scn, es, E, NBLK, NB);
    fill2_k<<<NB, 256, 0, stream>>>(es, scn, rowp, deg, dinv, colA, E, NBLK, NB, N);

    // one-time W transforms (cheap)
    wtrans_k<<<(32 * HF + 255) / 256, 256, 0, stream>>>(W1, W4_1, 32 * HF);
    wtrans_k<<<(16 * HF + 255) / 256, 256, 0, stream>>>(W2, W4_2, 16 * HF);
    wtrans_k<<<(16 * HF + 255) / 256, 256, 0, stream>>>(W3, W4_3, 16 * HF);

    int gRow = (N + 3) / 4;       // agg: 4 nodes/block
    int gRow64 = (N + 63) / 64;   // gemm: 64 rows/block
    // layer 1 (K=128)
    gemm4_k<128><<<gRow64, 256, 0, stream>>>(x, W4_1, dinv, U, N);
    agg_k<<<gRow, 256, 0, stream>>>(U, colA, rowp, deg, dinv, b1, P, N);
    // layer 2 (K=64)
    gemm4_k<64><<<gRow64, 256, 0, stream>>>(P, W4_2, dinv, U, N);
    agg_k<<<gRow, 256, 0, stream>>>(U, colA, rowp, deg, dinv, b2, P, N);
    // layer 3 (K=64)
    gemm4_k<64><<<gRow64, 256, 0, stream>>>(P, W4_3, dinv, U, N);
    agg_k<<<gRow, 256, 0, stream>>>(U, colA, rowp, deg, dinv, b3, P, N);

    pool_head_k<<<N_GRAPHS, 256, 0, stream>>>(P, batch, Wl, bl, outp, N);
}

// Round 6
// 425.552 us; speedup vs baseline: 4.7493x; 1.3698x over previous
//
#include <hip/hip_runtime.h>
#include <hip/hip_bf16.h>
#include <cstdint>
#include <cstddef>

static constexpr int N_NODES = 100000;
static constexpr int N_GRAPHS = 256;
static constexpr int HF = 64;

#define SCAN_T 256
#define SCAN_E 8
#define SCAN_CHUNK (SCAN_T * SCAN_E)

#define BSHIFT 9
#define BNODES 512
#define ECHUNK 16384
#define SRCBITS 17

typedef unsigned short u16;
typedef unsigned int u32;

// ---------- exclusive scan (3-pass) ----------
__global__ void scan1_k(const int* __restrict__ in, int* __restrict__ out,
                        int* __restrict__ sums, int n) {
    __shared__ int lds[SCAN_T];
    int t = threadIdx.x;
    int base = blockIdx.x * SCAN_CHUNK + t * SCAN_E;
    int v[SCAN_E];
    int s = 0;
#pragma unroll
    for (int i = 0; i < SCAN_E; ++i) {
        int idx = base + i;
        int x = (idx < n) ? in[idx] : 0;
        v[i] = s; s += x;
    }
    lds[t] = s; __syncthreads();
    for (int off = 1; off < SCAN_T; off <<= 1) {
        int a = (t >= off) ? lds[t - off] : 0;
        __syncthreads();
        lds[t] += a;
        __syncthreads();
    }
    int excl = (t == 0) ? 0 : lds[t - 1];
    if (t == SCAN_T - 1) sums[blockIdx.x] = lds[SCAN_T - 1];
#pragma unroll
    for (int i = 0; i < SCAN_E; ++i) {
        int idx = base + i;
        if (idx < n) out[idx] = excl + v[i];
    }
}

__global__ void scan2_k(int* __restrict__ sums, int nb) {
    __shared__ int lds[SCAN_T];
    int t = threadIdx.x;
    lds[t] = (t < nb) ? sums[t] : 0;
    __syncthreads();
    for (int off = 1; off < SCAN_T; off <<= 1) {
        int a = (t >= off) ? lds[t - off] : 0;
        __syncthreads();
        lds[t] += a;
        __syncthreads();
    }
    int excl = (t == 0) ? 0 : lds[t - 1];
    if (t < nb) sums[t] = excl;
}

__global__ void scan3_k(int* __restrict__ out, const int* __restrict__ sums, int n) {
    int idx = blockIdx.x * blockDim.x + threadIdx.x;
    if (idx < n) out[idx] += sums[idx / SCAN_CHUNK];
}

// ---------- per-chunk bucket histogram ----------
__global__ void bhist_k(const int* __restrict__ dst, int* __restrict__ cnt,
                        int E, int nblk, int NB) {
    __shared__ int c[256];
    int t = threadIdx.x;
    c[t] = 0;
    __syncthreads();
    int base = blockIdx.x * ECHUNK;
    for (int i = t; i < ECHUNK; i += 256) {
        int e = base + i;
        if (e >= E) break;
        atomicAdd(&c[dst[e] >> BSHIFT], 1);
    }
    __syncthreads();
    if (t < NB) cnt[t * nblk + blockIdx.x] = c[t];
}

// ---------- scatter edges into bucket partitions (packed: (d&511)<<17 | src) ----------
__global__ void scatter_k(const int* __restrict__ src, const int* __restrict__ dst,
                          const int* __restrict__ scn, int* __restrict__ es,
                          int E, int nblk, int NB) {
    __shared__ int offs[256];
    int t = threadIdx.x;
    if (t < NB) offs[t] = scn[t * nblk + blockIdx.x];
    __syncthreads();
    int base = blockIdx.x * ECHUNK;
    for (int i = t; i < ECHUNK; i += 256) {
        int e = base + i;
        if (e >= E) break;
        int d = dst[e];
        int b = d >> BSHIFT;
        int p = atomicAdd(&offs[b], 1);
        es[p] = ((d & (BNODES - 1)) << SRCBITS) | src[e];
    }
}

// ---------- per-bucket: local deg, row_ptr, dinv, CSR col fill ----------
__global__ void fill2_k(const int* __restrict__ es, const int* __restrict__ scn,
                        int* __restrict__ rowp, int* __restrict__ deg,
                        float* __restrict__ dinv, int* __restrict__ col,
                        int E, int nblk, int NB, int N) {
    __shared__ int ldeg[BNODES];
    __shared__ int rp[BNODES];
    __shared__ int ps[256];
    int b = blockIdx.x, t = threadIdx.x;
    int ebase = scn[b * nblk];
    int eend = (b + 1 < NB) ? scn[(b + 1) * nblk] : E;
    int d0 = b << BSHIFT;
    int nd = min(BNODES, N - d0);
    ldeg[t] = 0; ldeg[t + 256] = 0;
    __syncthreads();
    for (int e = ebase + t; e < eend; e += 256) atomicAdd(&ldeg[((u32)es[e]) >> SRCBITS], 1);
    __syncthreads();
    // exclusive scan of ldeg[0..511] -> rp
    int a0 = ldeg[2 * t], a1 = ldeg[2 * t + 1];
    ps[t] = a0 + a1;
    __syncthreads();
    for (int off = 1; off < 256; off <<= 1) {
        int v = (t >= off) ? ps[t - off] : 0;
        __syncthreads();
        ps[t] += v;
        __syncthreads();
    }
    int ex = (t == 0) ? 0 : ps[t - 1];
    rp[2 * t] = ex;
    rp[2 * t + 1] = ex + a0;
    __syncthreads();
    for (int i = t; i < nd; i += 256) {
        int d = d0 + i;
        rowp[d] = ebase + rp[i];
        int dg = ldeg[i];
        deg[d] = dg;
        dinv[d] = rsqrtf((float)(dg + 1));
    }
    __syncthreads();
    ldeg[t] = 0; ldeg[t + 256] = 0;  // reuse as position counters
    __syncthreads();
    for (int e = ebase + t; e < eend; e += 256) {
        u32 w = (u32)es[e];
        int li = w >> SRCBITS;
        int p = atomicAdd(&ldeg[li], 1);
        col[ebase + rp[li] + p] = (int)(w & ((1u << SRCBITS) - 1));
    }
}

// ---------- W transpose: W4[k4*64+c] = {W[4k4..4k4+3][c]} ----------
__global__ void wtrans_k(const float* __restrict__ W, float4* __restrict__ W4, int total) {
    int idx = blockIdx.x * blockDim.x + threadIdx.x;
    if (idx >= total) return;
    int k4 = idx >> 6, c = idx & 63;
    W4[idx] = make_float4(W[(4 * k4 + 0) * HF + c], W[(4 * k4 + 1) * HF + c],
                          W[(4 * k4 + 2) * HF + c], W[(4 * k4 + 3) * HF + c]);
}

// ---------- u = bf16((in @ W) * dinv[row])  (LDS-tiled, pressure-capped) ----------
template <int K>
__global__ __launch_bounds__(256, 4) void gemm4_k(const float* __restrict__ in,
                                                  const float4* __restrict__ W4,
                                                  const float* __restrict__ dinv,
                                                  __hip_bfloat16* __restrict__ u, int n) {
    __shared__ float4 Wl[16 * HF];   // W chunk: [16 k4][64 col], 16 KB
    __shared__ float4 Xl[64 * 17];   // x chunk: [64 row][16 k4 + pad], 17.4 KB
    int t = threadIdx.x;
    int wave = t >> 6, lane = t & 63;
    int rb = blockIdx.x * 64;
    float acc[16];
#pragma unroll
    for (int i = 0; i < 16; ++i) acc[i] = 0.f;
    constexpr int NC = K / 64;
#pragma unroll 1
    for (int kc = 0; kc < NC; ++kc) {
        const float4* Wc = W4 + kc * 16 * HF;
#pragma unroll 1
        for (int i = t; i < 16 * HF; i += 256) Wl[i] = Wc[i];
        {
            int r = t >> 4, q = t & 15;
#pragma unroll 1
            for (int i = 0; i < 4; ++i) {
                int row = r + i * 16;
                int gr = rb + row;
                float4 v = (gr < n)
                    ? *(const float4*)(in + (size_t)gr * K + kc * 64 + q * 4)
                    : make_float4(0.f, 0.f, 0.f, 0.f);
                Xl[row * 17 + q] = v;
            }
        }
        __syncthreads();
        int r0 = wave * 16;
#pragma unroll 1
        for (int k4 = 0; k4 < 16; ++k4) {
            float4 w = Wl[k4 * HF + lane];
#pragma unroll
            for (int r = 0; r < 16; ++r) {
                float4 v = Xl[(r0 + r) * 17 + k4];
                acc[r] = fmaf(v.x, w.x, fmaf(v.y, w.y, fmaf(v.z, w.z, fmaf(v.w, w.w, acc[r]))));
            }
        }
        __syncthreads();
    }
#pragma unroll 1
    for (int r = 0; r < 16; ++r) {
        int row = rb + wave * 16 + r;
        if (row < n) u[(size_t)row * HF + lane] = __float2bfloat16(acc[r] * dinv[row]);
    }
}

// ---------- aggregation (bf16 gather): out[v] = relu(dinv[v]*(sum u[s] + u[v]) + b) ----------
// Half-wave (32 lanes) per node; lane covers features {2sl, 2sl+1} via one u32 load (128B/row).
__global__ __launch_bounds__(256) void agg2_k(const u32* __restrict__ u,
                                              const int* __restrict__ col,
                                              const int* __restrict__ rowp,
                                              const int* __restrict__ deg,
                                              const float* __restrict__ dinv,
                                              const float* __restrict__ bias,
                                              float* __restrict__ out, int n) {
    int t = threadIdx.x;
    int wave = t >> 6, lane = t & 63;
    int sl = lane & 31;
    int v = blockIdx.x * 8 + wave * 2 + (lane >> 5);
    if (v >= n) return;
    u32 q = u[(size_t)v * 32 + sl];  // self loop
    float ax = __uint_as_float(q << 16);
    float ay = __uint_as_float(q & 0xffff0000u);
    int start = rowp[v];
    int nE = deg[v];
    for (int e = 0; e < nE;) {
        int m = min(32, nE - e);
        int c = (sl < m) ? col[start + e + sl] : 0;
        int i = 0;
        for (; i + 4 <= m; i += 4) {
            int s0 = __shfl(c, i, 32),     s1 = __shfl(c, i + 1, 32);
            int s2 = __shfl(c, i + 2, 32), s3 = __shfl(c, i + 3, 32);
            u32 q0 = u[(size_t)s0 * 32 + sl];
            u32 q1 = u[(size_t)s1 * 32 + sl];
            u32 q2 = u[(size_t)s2 * 32 + sl];
            u32 q3 = u[(size_t)s3 * 32 + sl];
            ax += __uint_as_float(q0 << 16);         ay += __uint_as_float(q0 & 0xffff0000u);
            ax += __uint_as_float(q1 << 16);         ay += __uint_as_float(q1 & 0xffff0000u);
            ax += __uint_as_float(q2 << 16);         ay += __uint_as_float(q2 & 0xffff0000u);
            ax += __uint_as_float(q3 << 16);         ay += __uint_as_float(q3 & 0xffff0000u);
        }
        for (; i < m; ++i) {
            int s = __shfl(c, i, 32);
            u32 qq = u[(size_t)s * 32 + sl];
            ax += __uint_as_float(qq << 16);
            ay += __uint_as_float(qq & 0xffff0000u);
        }
        e += m;
    }
    float dv = dinv[v];
    float2 o;
    o.x = fmaxf(fmaf(ax, dv, bias[2 * sl]), 0.f);
    o.y = fmaxf(fmaf(ay, dv, bias[2 * sl + 1]), 0.f);
    ((float2*)out)[(size_t)v * 32 + sl] = o;
}

// ---------- fused mean-pool + linear head ----------
__device__ __forceinline__ int lower_bound_i(const int* a, int n, int key) {
    int lo = 0, hi = n;
    while (lo < hi) { int mid = (lo + hi) >> 1; if (a[mid] < key) lo = mid + 1; else hi = mid; }
    return lo;
}

__global__ void pool_head_k(const float* __restrict__ h, const int* __restrict__ batch,
                            const float* __restrict__ Wl, const float* __restrict__ bl,
                            float* __restrict__ out, int n) {
    __shared__ float ssum[4][HF];
    __shared__ float smean[HF];
    int g = blockIdx.x;
    int wave = threadIdx.x >> 6, lane = threadIdx.x & 63;
    int start = lower_bound_i(batch, n, g);
    int end = lower_bound_i(batch, n, g + 1);
    float acc = 0.f;
    for (int v = start + wave; v < end; v += 4) acc += h[(size_t)v * HF + lane];
    ssum[wave][lane] = acc;
    __syncthreads();
    if (wave == 0) {
        float s = ssum[0][lane] + ssum[1][lane] + ssum[2][lane] + ssum[3][lane];
        float cnt = (float)(end - start);
        smean[lane] = s / fmaxf(cnt, 1.f);
    }
    __syncthreads();
    if (threadIdx.x < 2) {
        float o = bl[threadIdx.x];
        for (int j = 0; j < HF; ++j) o += smean[j] * Wl[j * 2 + threadIdx.x];
        out[g * 2 + threadIdx.x] = o;
    }
}

extern "C" void kernel_launch(void* const* d_in, const int* in_sizes, int n_in,
                              void* d_out, int out_size, void* d_ws, size_t ws_size,
                              hipStream_t stream) {
    const float* x     = (const float*)d_in[0];
    const int*   ei    = (const int*)d_in[1];
    const int*   batch = (const int*)d_in[2];
    const float* W1 = (const float*)d_in[3];
    const float* b1 = (const float*)d_in[4];
    const float* W2 = (const float*)d_in[5];
    const float* b2 = (const float*)d_in[6];
    const float* W3 = (const float*)d_in[7];
    const float* b3 = (const float*)d_in[8];
    const float* Wl = (const float*)d_in[9];
    const float* bl = (const float*)d_in[10];
    float* outp = (float*)d_out;

    const int N = N_NODES;
    const int E = in_sizes[1] / 2;
    const int NB = (N + BNODES - 1) >> BSHIFT;        // 196 buckets
    const int NBLK = (E + ECHUNK - 1) / ECHUNK;       // edge chunks
    const int M = NB * NBLK;                          // (bucket, chunk) counts

    char* ws = (char*)d_ws;
    size_t off = 0;
    auto alloc = [&](size_t bytes) {
        void* p = ws + off;
        off = (off + bytes + 255) & ~size_t(255);
        return p;
    };
    size_t ubytes = (size_t)N * HF * 2;
    if ((size_t)E * 4 > ubytes) ubytes = (size_t)E * 4;
    float*  P    = (float*)alloc((size_t)N * HF * 4);
    void*   Uv   = alloc(ubytes);                     // bf16 u; also sorted edges pre-gemm
    int*    colA = (int*)alloc((size_t)E * 4);
    int*    deg  = (int*)alloc((size_t)N * 4);
    float*  dinv = (float*)alloc((size_t)N * 4);
    int*    rowp = (int*)alloc((size_t)N * 4);
    int*    cnt  = (int*)alloc((size_t)M * 4);
    int*    scn  = (int*)alloc((size_t)M * 4);
    int*    sums = (int*)alloc(1024);
    float4* W4_1 = (float4*)alloc((size_t)(128 / 4) * HF * 16);
    float4* W4_2 = (float4*)alloc((size_t)(64 / 4) * HF * 16);
    float4* W4_3 = (float4*)alloc((size_t)(64 / 4) * HF * 16);
    __hip_bfloat16* U = (__hip_bfloat16*)Uv;
    u32* U32 = (u32*)Uv;
    int* es  = (int*)Uv;
    (void)ws_size; (void)n_in; (void)out_size;

    const int* src = ei;
    const int* dst = ei + E;

    // ---- build bucket-sorted edge list + CSR ----
    bhist_k<<<NBLK, 256, 0, stream>>>(dst, cnt, E, NBLK, NB);
    int nb = (M + SCAN_CHUNK - 1) / SCAN_CHUNK;
    scan1_k<<<nb, SCAN_T, 0, stream>>>(cnt, scn, sums, M);
    scan2_k<<<1, SCAN_T, 0, stream>>>(sums, nb);
    scan3_k<<<(M + 255) / 256, 256, 0, stream>>>(scn, sums, M);
    scatter_k<<<NBLK, 256, 0, stream>>>(src, dst, scn, es, E, NBLK, NB);
    fill2_k<<<NB, 256, 0, stream>>>(es, scn, rowp, deg, dinv, colA, E, NBLK, NB, N);

    // one-time W transforms (cheap)
    wtrans_k<<<(32 * HF + 255) / 256, 256, 0, stream>>>(W1, W4_1, 32 * HF);
    wtrans_k<<<(16 * HF + 255) / 256, 256, 0, stream>>>(W2, W4_2, 16 * HF);
    wtrans_k<<<(16 * HF + 255) / 256, 256, 0, stream>>>(W3, W4_3, 16 * HF);

    int gRow8  = (N + 7) / 8;     // agg: 8 nodes/block (half-wave per node)
    int gRow64 = (N + 63) / 64;   // gemm: 64 rows/block
    // layer 1 (K=128)
    gemm4_k<128><<<gRow64, 256, 0, stream>>>(x, W4_1, dinv, U, N);
    agg2_k<<<gRow8, 256, 0, stream>>>(U32, colA, rowp, deg, dinv, b1, P, N);
    // layer 2 (K=64)
    gemm4_k<64><<<gRow64, 256, 0, stream>>>(P, W4_2, dinv, U, N);
    agg2_k<<<gRow8, 256, 0, stream>>>(U32, colA, rowp, deg, dinv, b2, P, N);
    // layer 3 (K=64)
    gemm4_k<64><<<gRow64, 256, 0, stream>>>(P, W4_3, dinv, U, N);
    agg2_k<<<gRow8, 256, 0, stream>>>(U32, colA, rowp, deg, dinv, b3, P, N);

    pool_head_k<<<N_GRAPHS, 256, 0, stream>>>(P, batch, Wl, bl, outp, N);
}

// Round 7
// 385.225 us; speedup vs baseline: 5.2465x; 1.1047x over previous
//
#include <hip/hip_runtime.h>
#include <hip/hip_bf16.h>
#include <cstdint>
#include <cstddef>

static constexpr int N_NODES = 100000;
static constexpr int N_GRAPHS = 256;
static constexpr int HF = 64;

#define SCAN_T 256
#define SCAN_E 8
#define SCAN_CHUNK (SCAN_T * SCAN_E)

#define BSHIFT 9
#define BNODES 512
#define ECHUNK 4096
#define SRCBITS 17

typedef unsigned short u16;
typedef unsigned int u32;

// ---------- exclusive scan (3-pass) ----------
__global__ void scan1_k(const int* __restrict__ in, int* __restrict__ out,
                        int* __restrict__ sums, int n) {
    __shared__ int lds[SCAN_T];
    int t = threadIdx.x;
    int base = blockIdx.x * SCAN_CHUNK + t * SCAN_E;
    int v[SCAN_E];
    int s = 0;
#pragma unroll
    for (int i = 0; i < SCAN_E; ++i) {
        int idx = base + i;
        int x = (idx < n) ? in[idx] : 0;
        v[i] = s; s += x;
    }
    lds[t] = s; __syncthreads();
    for (int off = 1; off < SCAN_T; off <<= 1) {
        int a = (t >= off) ? lds[t - off] : 0;
        __syncthreads();
        lds[t] += a;
        __syncthreads();
    }
    int excl = (t == 0) ? 0 : lds[t - 1];
    if (t == SCAN_T - 1) sums[blockIdx.x] = lds[SCAN_T - 1];
#pragma unroll
    for (int i = 0; i < SCAN_E; ++i) {
        int idx = base + i;
        if (idx < n) out[idx] = excl + v[i];
    }
}

__global__ void scan2_k(int* __restrict__ sums, int nb) {
    __shared__ int lds[SCAN_T];
    int t = threadIdx.x;
    lds[t] = (t < nb) ? sums[t] : 0;
    __syncthreads();
    for (int off = 1; off < SCAN_T; off <<= 1) {
        int a = (t >= off) ? lds[t - off] : 0;
        __syncthreads();
        lds[t] += a;
        __syncthreads();
    }
    int excl = (t == 0) ? 0 : lds[t - 1];
    if (t < nb) sums[t] = excl;
}

__global__ void scan3_k(int* __restrict__ out, const int* __restrict__ sums, int n) {
    int idx = blockIdx.x * blockDim.x + threadIdx.x;
    if (idx < n) out[idx] += sums[idx / SCAN_CHUNK];
}

// ---------- per-chunk bucket histogram ----------
__global__ void bhist_k(const int* __restrict__ dst, int* __restrict__ cnt,
                        int E, int nblk, int NB) {
    __shared__ int c[256];
    int t = threadIdx.x;
    c[t] = 0;
    __syncthreads();
    int base = blockIdx.x * ECHUNK;
    int m = min(ECHUNK, E - base);
    for (int i = t; i < m; i += 256) atomicAdd(&c[dst[base + i] >> BSHIFT], 1);
    __syncthreads();
    if (t < NB) cnt[t * nblk + blockIdx.x] = c[t];
}

// ---------- scatter edges into bucket partitions (packed: (d&511)<<17 | src) ----------
__global__ void scatter_k(const int* __restrict__ src, const int* __restrict__ dst,
                          const int* __restrict__ scn, int* __restrict__ es,
                          int E, int nblk, int NB) {
    __shared__ int offs[256];
    int t = threadIdx.x;
    if (t < NB) offs[t] = scn[t * nblk + blockIdx.x];
    __syncthreads();
    int base = blockIdx.x * ECHUNK;
    int m = min(ECHUNK, E - base);
    for (int i = t; i < m; i += 256) {
        int e = base + i;
        int d = dst[e];
        int b = d >> BSHIFT;
        int p = atomicAdd(&offs[b], 1);
        es[p] = ((d & (BNODES - 1)) << SRCBITS) | src[e];
    }
}

// ---------- per-bucket: local deg, row_ptr, dinv, CSR col fill (512 thr) ----------
__global__ __launch_bounds__(512) void fill2_k(const int* __restrict__ es,
                                               const int* __restrict__ scn,
                                               int* __restrict__ rowp, int* __restrict__ deg,
                                               float* __restrict__ dinv, int* __restrict__ col,
                                               int E, int nblk, int NB, int N) {
    __shared__ int ldeg[BNODES];
    __shared__ int rp[BNODES];
    __shared__ int tmp[BNODES];
    int b = blockIdx.x, t = threadIdx.x;
    int ebase = scn[b * nblk];
    int eend = (b + 1 < NB) ? scn[(b + 1) * nblk] : E;
    int d0 = b << BSHIFT;
    int nd = min(BNODES, N - d0);
    ldeg[t] = 0;
    __syncthreads();
    for (int e = ebase + t; e < eend; e += 512) atomicAdd(&ldeg[((u32)es[e]) >> SRCBITS], 1);
    __syncthreads();
    int a = ldeg[t];
    tmp[t] = a;
    __syncthreads();
    for (int off = 1; off < BNODES; off <<= 1) {
        int v = (t >= off) ? tmp[t - off] : 0;
        __syncthreads();
        tmp[t] += v;
        __syncthreads();
    }
    rp[t] = tmp[t] - a;   // exclusive
    __syncthreads();
    if (t < nd) {
        int d = d0 + t;
        rowp[d] = ebase + rp[t];
        deg[d] = a;
        dinv[d] = rsqrtf((float)(a + 1));
    }
    ldeg[t] = 0;  // reuse as position counters
    __syncthreads();
    for (int e = ebase + t; e < eend; e += 512) {
        u32 w = (u32)es[e];
        int li = w >> SRCBITS;
        int p = atomicAdd(&ldeg[li], 1);
        col[ebase + rp[li] + p] = (int)(w & ((1u << SRCBITS) - 1));
    }
}

// ---------- W transpose: W4[k4*64+c] = {W[4k4..4k4+3][c]} ----------
__global__ void wtrans_k(const float* __restrict__ W, float4* __restrict__ W4, int total) {
    int idx = blockIdx.x * blockDim.x + threadIdx.x;
    if (idx >= total) return;
    int k4 = idx >> 6, c = idx & 63;
    W4[idx] = make_float4(W[(4 * k4 + 0) * HF + c], W[(4 * k4 + 1) * HF + c],
                          W[(4 * k4 + 2) * HF + c], W[(4 * k4 + 3) * HF + c]);
}

// ---------- u = bf16((in @ W) * dinv[row])  (LDS-tiled, pressure-capped) ----------
template <int K>
__global__ __launch_bounds__(256, 4) void gemm4_k(const float* __restrict__ in,
                                                  const float4* __restrict__ W4,
                                                  const float* __restrict__ dinv,
                                                  __hip_bfloat16* __restrict__ u, int n) {
    __shared__ float4 Wl[16 * HF];   // W chunk: [16 k4][64 col], 16 KB
    __shared__ float4 Xl[64 * 17];   // x chunk: [64 row][16 k4 + pad], 17.4 KB
    int t = threadIdx.x;
    int wave = t >> 6, lane = t & 63;
    int rb = blockIdx.x * 64;
    float acc[16];
#pragma unroll
    for (int i = 0; i < 16; ++i) acc[i] = 0.f;
    constexpr int NC = K / 64;
#pragma unroll 1
    for (int kc = 0; kc < NC; ++kc) {
        const float4* Wc = W4 + kc * 16 * HF;
#pragma unroll 1
        for (int i = t; i < 16 * HF; i += 256) Wl[i] = Wc[i];
        {
            int r = t >> 4, q = t & 15;
#pragma unroll 1
            for (int i = 0; i < 4; ++i) {
                int row = r + i * 16;
                int gr = rb + row;
                float4 v = (gr < n)
                    ? *(const float4*)(in + (size_t)gr * K + kc * 64 + q * 4)
                    : make_float4(0.f, 0.f, 0.f, 0.f);
                Xl[row * 17 + q] = v;
            }
        }
        __syncthreads();
        int r0 = wave * 16;
#pragma unroll 1
        for (int k4 = 0; k4 < 16; ++k4) {
            float4 w = Wl[k4 * HF + lane];
#pragma unroll
            for (int r = 0; r < 16; ++r) {
                float4 v = Xl[(r0 + r) * 17 + k4];
                acc[r] = fmaf(v.x, w.x, fmaf(v.y, w.y, fmaf(v.z, w.z, fmaf(v.w, w.w, acc[r]))));
            }
        }
        __syncthreads();
    }
#pragma unroll 1
    for (int r = 0; r < 16; ++r) {
        int row = rb + wave * 16 + r;
        if (row < n) u[(size_t)row * HF + lane] = __float2bfloat16(acc[r] * dinv[row]);
    }
}

// ---------- aggregation (bf16 gather): out[v] = relu(dinv[v]*(sum u[s] + u[v]) + b) ----------
// Half-wave (32 lanes) per node; lane covers features {2sl, 2sl+1} via one u32 load (128B/row).
__global__ __launch_bounds__(256) void agg2_k(const u32* __restrict__ u,
                                              const int* __restrict__ col,
                                              const int* __restrict__ rowp,
                                              const int* __restrict__ deg,
                                              const float* __restrict__ dinv,
                                              const float* __restrict__ bias,
                                              float* __restrict__ out, int n) {
    int t = threadIdx.x;
    int wave = t >> 6, lane = t & 63;
    int sl = lane & 31;
    int v = blockIdx.x * 8 + wave * 2 + (lane >> 5);
    if (v >= n) return;
    u32 q = u[(size_t)v * 32 + sl];  // self loop
    float ax = __uint_as_float(q << 16);
    float ay = __uint_as_float(q & 0xffff0000u);
    int start = rowp[v];
    int nE = deg[v];
    for (int e = 0; e < nE;) {
        int m = min(32, nE - e);
        int c = (sl < m) ? col[start + e + sl] : 0;
        int i = 0;
        for (; i + 8 <= m; i += 8) {
            int s0 = __shfl(c, i, 32),     s1 = __shfl(c, i + 1, 32);
            int s2 = __shfl(c, i + 2, 32), s3 = __shfl(c, i + 3, 32);
            int s4 = __shfl(c, i + 4, 32), s5 = __shfl(c, i + 5, 32);
            int s6 = __shfl(c, i + 6, 32), s7 = __shfl(c, i + 7, 32);
            u32 q0 = u[(size_t)s0 * 32 + sl];
            u32 q1 = u[(size_t)s1 * 32 + sl];
            u32 q2 = u[(size_t)s2 * 32 + sl];
            u32 q3 = u[(size_t)s3 * 32 + sl];
            u32 q4 = u[(size_t)s4 * 32 + sl];
            u32 q5 = u[(size_t)s5 * 32 + sl];
            u32 q6 = u[(size_t)s6 * 32 + sl];
            u32 q7 = u[(size_t)s7 * 32 + sl];
            ax += __uint_as_float(q0 << 16);  ay += __uint_as_float(q0 & 0xffff0000u);
            ax += __uint_as_float(q1 << 16);  ay += __uint_as_float(q1 & 0xffff0000u);
            ax += __uint_as_float(q2 << 16);  ay += __uint_as_float(q2 & 0xffff0000u);
            ax += __uint_as_float(q3 << 16);  ay += __uint_as_float(q3 & 0xffff0000u);
            ax += __uint_as_float(q4 << 16);  ay += __uint_as_float(q4 & 0xffff0000u);
            ax += __uint_as_float(q5 << 16);  ay += __uint_as_float(q5 & 0xffff0000u);
            ax += __uint_as_float(q6 << 16);  ay += __uint_as_float(q6 & 0xffff0000u);
            ax += __uint_as_float(q7 << 16);  ay += __uint_as_float(q7 & 0xffff0000u);
        }
        for (; i < m; ++i) {
            int s = __shfl(c, i, 32);
            u32 qq = u[(size_t)s * 32 + sl];
            ax += __uint_as_float(qq << 16);
            ay += __uint_as_float(qq & 0xffff0000u);
        }
        e += m;
    }
    float dv = dinv[v];
    float2 o;
    o.x = fmaxf(fmaf(ax, dv, bias[2 * sl]), 0.f);
    o.y = fmaxf(fmaf(ay, dv, bias[2 * sl + 1]), 0.f);
    ((float2*)out)[(size_t)v * 32 + sl] = o;
}

// ---------- fused mean-pool + linear head ----------
__device__ __forceinline__ int lower_bound_i(const int* a, int n, int key) {
    int lo = 0, hi = n;
    while (lo < hi) { int mid = (lo + hi) >> 1; if (a[mid] < key) lo = mid + 1; else hi = mid; }
    return lo;
}

__global__ void pool_head_k(const float* __restrict__ h, const int* __restrict__ batch,
                            const float* __restrict__ Wl, const float* __restrict__ bl,
                            float* __restrict__ out, int n) {
    __shared__ float ssum[4][HF];
    __shared__ float smean[HF];
    int g = blockIdx.x;
    int wave = threadIdx.x >> 6, lane = threadIdx.x & 63;
    int start = lower_bound_i(batch, n, g);
    int end = lower_bound_i(batch, n, g + 1);
    float acc = 0.f;
    for (int v = start + wave; v < end; v += 4) acc += h[(size_t)v * HF + lane];
    ssum[wave][lane] = acc;
    __syncthreads();
    if (wave == 0) {
        float s = ssum[0][lane] + ssum[1][lane] + ssum[2][lane] + ssum[3][lane];
        float cnt = (float)(end - start);
        smean[lane] = s / fmaxf(cnt, 1.f);
    }
    __syncthreads();
    if (threadIdx.x < 2) {
        float o = bl[threadIdx.x];
        for (int j = 0; j < HF; ++j) o += smean[j] * Wl[j * 2 + threadIdx.x];
        out[g * 2 + threadIdx.x] = o;
    }
}

extern "C" void kernel_launch(void* const* d_in, const int* in_sizes, int n_in,
                              void* d_out, int out_size, void* d_ws, size_t ws_size,
                              hipStream_t stream) {
    const float* x     = (const float*)d_in[0];
    const int*   ei    = (const int*)d_in[1];
    const int*   batch = (const int*)d_in[2];
    const float* W1 = (const float*)d_in[3];
    const float* b1 = (const float*)d_in[4];
    const float* W2 = (const float*)d_in[5];
    const float* b2 = (const float*)d_in[6];
    const float* W3 = (const float*)d_in[7];
    const float* b3 = (const float*)d_in[8];
    const float* Wl = (const float*)d_in[9];
    const float* bl = (const float*)d_in[10];
    float* outp = (float*)d_out;

    const int N = N_NODES;
    const int E = in_sizes[1] / 2;
    const int NB = (N + BNODES - 1) >> BSHIFT;        // 196 buckets
    const int NBLK = (E + ECHUNK - 1) / ECHUNK;       // edge chunks (~782)
    const int M = NB * NBLK;                          // (bucket, chunk) counts

    char* ws = (char*)d_ws;
    size_t off = 0;
    auto alloc = [&](size_t bytes) {
        void* p = ws + off;
        off = (off + bytes + 255) & ~size_t(255);
        return p;
    };
    size_t ubytes = (size_t)N * HF * 2;
    if ((size_t)E * 4 > ubytes) ubytes = (size_t)E * 4;
    float*  P    = (float*)alloc((size_t)N * HF * 4);
    void*   Uv   = alloc(ubytes);                     // bf16 u; also sorted edges pre-gemm
    int*    colA = (int*)alloc((size_t)E * 4);
    int*    deg  = (int*)alloc((size_t)N * 4);
    float*  dinv = (float*)alloc((size_t)N * 4);
    int*    rowp = (int*)alloc((size_t)N * 4);
    int*    cnt  = (int*)alloc((size_t)M * 4);
    int*    scn  = (int*)alloc((size_t)M * 4);
    int*    sums = (int*)alloc(4096);
    float4* W4_1 = (float4*)alloc((size_t)(128 / 4) * HF * 16);
    float4* W4_2 = (float4*)alloc((size_t)(64 / 4) * HF * 16);
    float4* W4_3 = (float4*)alloc((size_t)(64 / 4) * HF * 16);
    __hip_bfloat16* U = (__hip_bfloat16*)Uv;
    u32* U32 = (u32*)Uv;
    int* es  = (int*)Uv;
    (void)ws_size; (void)n_in; (void)out_size;

    const int* src = ei;
    const int* dst = ei + E;

    // ---- build bucket-sorted edge list + CSR ----
    bhist_k<<<NBLK, 256, 0, stream>>>(dst, cnt, E, NBLK, NB);
    int nb = (M + SCAN_CHUNK - 1) / SCAN_CHUNK;
    scan1_k<<<nb, SCAN_T, 0, stream>>>(cnt, scn, sums, M);
    scan2_k<<<1, SCAN_T, 0, stream>>>(sums, nb);
    scan3_k<<<(M + 255) / 256, 256, 0, stream>>>(scn, sums, M);
    scatter_k<<<NBLK, 256, 0, stream>>>(src, dst, scn, es, E, NBLK, NB);
    fill2_k<<<NB, 512, 0, stream>>>(es, scn, rowp, deg, dinv, colA, E, NBLK, NB, N);

    // one-time W transforms (cheap)
    wtrans_k<<<(32 * HF + 255) / 256, 256, 0, stream>>>(W1, W4_1, 32 * HF);
    wtrans_k<<<(16 * HF + 255) / 256, 256, 0, stream>>>(W2, W4_2, 16 * HF);
    wtrans_k<<<(16 * HF + 255) / 256, 256, 0, stream>>>(W3, W4_3, 16 * HF);

    int gRow8  = (N + 7) / 8;     // agg: 8 nodes/block (half-wave per node)
    int gRow64 = (N + 63) / 64;   // gemm: 64 rows/block
    // layer 1 (K=128)
    gemm4_k<128><<<gRow64, 256, 0, stream>>>(x, W4_1, dinv, U, N);
    agg2_k<<<gRow8, 256, 0, stream>>>(U32, colA, rowp, deg, dinv, b1, P, N);
    // layer 2 (K=64)
    gemm4_k<64><<<gRow64, 256, 0, stream>>>(P, W4_2, dinv, U, N);
    agg2_k<<<gRow8, 256, 0, stream>>>(U32, colA, rowp, deg, dinv, b2, P, N);
    // layer 3 (K=64)
    gemm4_k<64><<<gRow64, 256, 0, stream>>>(P, W4_3, dinv, U, N);
    agg2_k<<<gRow8, 256, 0, stream>>>(U32, colA, rowp, deg, dinv, b3, P, N);

    pool_head_k<<<N_GRAPHS, 256, 0, stream>>>(P, batch, Wl, bl, outp, N);
}